// Round 10
// baseline (35.860 us; speedup 1.0000x reference)
//
#include <hip/hip_runtime.h>
#include <math.h>

#define B_ 16
#define L_ 1024
#define IMG 224
#define PIX (IMG*IMG)        /* 50176 */
#define NBD 128
#define MAGIC 0x1357BEEFu

/* ---- ws layout (uint/float views share the buffer) ----
   OFF_DONE : done[16][8][8] flag cells (prod d -> cons). Single consumer per
              cell; consumer resets to 0 after use. Poison 0xAA..AA != MAGIC
              and 0 != MAGIC, so no init pass is ever needed.
   OFF_A    : a[128]    OFF_TERM: term[128]
   OFF_GPMIN/GPMAX: g min/max partials[128]
   OFF_T    : tbl[16][224][16]   OFF_G: g[16][224][224]
*/
#define OFF_DONE  0
#define OFF_A     1024
#define OFF_TERM  1152
#define OFF_GPMIN 1280
#define OFF_GPMAX 1408
#define OFF_T     1536                 /* 57344 floats */
#define OFF_G     58880                /* 802816 floats */

#define CPAD(k) ((((k) >> 4) * 17) + ((k) & 15))

__device__ __forceinline__ float cclip(float xn) {
    return fminf(fmaxf(xn, -1.0f + 1e-6f), 1.0f - 1e-6f);
}
__device__ __forceinline__ int bucketf(float c) {
    int k = (int)((c + 1.0f) * 512.0f);
    return min(1023, max(0, k));
}

template <int NTHR>
__device__ __forceinline__ void block_minmax_share(float mn, float mx, float* red) {
    #pragma unroll
    for (int off = 32; off > 0; off >>= 1) {
        mn = fminf(mn, __shfl_down(mn, off));
        mx = fmaxf(mx, __shfl_down(mx, off));
    }
    const int lane = threadIdx.x & 63;
    const int wave = threadIdx.x >> 6;
    if (lane == 0) { red[2 + wave*2] = mn; red[3 + wave*2] = mx; }
    __syncthreads();
    if (threadIdx.x == 0) {
        #pragma unroll
        for (int w = 1; w < NTHR/64; ++w) {
            mn = fminf(mn, red[2 + w*2]);
            mx = fmaxf(mx, red[3 + w*2]);
        }
        red[0] = mn; red[1] = mx;
    }
    __syncthreads();
}

/* K1: one block per (b,d), 1024 threads.
   Phases (a)-(e) identical to R9's k_bd (sort + analytic pair min/max +
   sample-table d-slice). Then: mesh handoff (7 outgoing flag cells, 7
   incoming), and this block resizes rows [d*28, d*28+28) of batch b's
   224x224 image, writing g + one min/max partial. */
__global__ __launch_bounds__(1024) void k_bd(const float* __restrict__ x,
                                             float* __restrict__ wsf,
                                             unsigned* __restrict__ wsu) {
    __shared__ float red[36];
    __shared__ __align__(16) float POOL[4352];   /* corig|arr|cnt|pref, 17KB */
    float* corig = POOL;
    float* arr   = POOL + 1024;
    int*   cnt   = (int*)(POOL + 2048);          /* 1090 ints */
    int*   pref  = ((int*)(POOL + 2048)) + 1090; /* 1090 ints */
    float* ylds  = POOL;                         /* resize-phase overlay */

    const int bd = blockIdx.x;
    const int b = bd >> 3, d = bd & 7;
    const int t = threadIdx.x;

    /* (a) global x min/max, redundant per block */
    {
        float mn = 1e30f, mx = -1e30f;
        const float4* xv = (const float4*)x;
        #pragma unroll 4
        for (int i = t; i < 32768; i += 1024) {
            float4 v = xv[i];
            mn = fminf(mn, fminf(fminf(v.x, v.y), fminf(v.z, v.w)));
            mx = fmaxf(mx, fmaxf(fmaxf(v.x, v.y), fmaxf(v.z, v.w)));
        }
        block_minmax_share<1024>(mn, mx, red);
    }
    float lo = red[0], hi = red[1], r = hi - lo, sc, sh;
    if (r < 1e-8f) { sc = 0.0f; sh = -1.0f; }
    else           { sc = 2.0f / (r + 1e-8f); sh = -lo*sc - 1.0f; }

    /* (b) load row (1/thread), zero counts */
    cnt[t] = 0;
    if (t < 66) cnt[1024 + t] = 0;
    float c = cclip(x[((size_t)(b*L_ + t))*8 + d]*sc + sh);
    corig[t] = c;
    block_minmax_share<1024>(c, c, red);
    float cMin = red[0], cMax = red[1];

    atomicAdd(&cnt[CPAD(bucketf(c))], 1);
    __syncthreads();

    if (t < 64) {
        int s = 0;
        #pragma unroll
        for (int e = 0; e < 16; ++e) s += cnt[t*17 + e];
        int v = s;
        #pragma unroll
        for (int o = 1; o < 64; o <<= 1) {
            int u = __shfl_up(v, o);
            if (t >= o) v += u;
        }
        int run = v - s;
        #pragma unroll
        for (int e = 0; e < 16; ++e) { pref[t*17 + e] = run; run += cnt[t*17 + e]; }
        if (t == 63) pref[CPAD(1024)] = run;
    }
    __syncthreads();
    cnt[CPAD(t)] = pref[CPAD(t)];
    __syncthreads();
    {
        int p = atomicAdd(&cnt[CPAD(bucketf(c))], 1);
        arr[p] = c;
    }
    __syncthreads();

    /* (c) pair-min via neighbor span of -c_i */
    float rowmin = 1e30f;
    {
        float ci = c;
        float si = sqrtf(fmaxf(1.0f - ci*ci, 0.0f));
        int kt = bucketf(-ci);
        int lo_p = pref[CPAD(kt)], hi_p = pref[CPAD(kt + 1)];
        int start = lo_p, end = hi_p;
        if (lo_p > 0)   start = pref[CPAD(bucketf(arr[lo_p - 1]))];
        if (hi_p < L_)  end   = pref[CPAD(bucketf(arr[hi_p]) + 1)];
        for (int p = start; p < end; ++p) {
            float cj = arr[p];
            float sj = sqrtf(fmaxf(1.0f - cj*cj, 0.0f));
            rowmin = fminf(rowmin, ci*cj - si*sj);
        }
    }
    block_minmax_share<1024>(rowmin, -1e30f, red);
    if (t == 0) {
        float plo = red[0];
        float phi = fmaxf(2.0f*cMin*cMin - 1.0f, 2.0f*cMax*cMax - 1.0f);
        float rr  = phi - plo;
        float inv = (rr < 1e-8f) ? 0.0f : 1.0f / (rr + 1e-8f);
        wsf[OFF_A + bd]    = inv * 0.125f;
        wsf[OFF_TERM + bd] = plo * inv * 0.125f;
    }

    /* (e) sample table d-slice */
    if (t < IMG) {
        const float SC = 1024.0f / 224.0f;
        float syf = (t + 0.5f)*SC - 0.5f;
        int i0 = (int)floorf(syf);
        i0 = max(0, min(i0, L_ - 2));
        float f = syf - (float)i0;
        float ca = corig[i0], cb = corig[i0 + 1];
        float sa = sqrtf(fmaxf(1.0f - ca*ca, 0.0f));
        float sb = sqrtf(fmaxf(1.0f - cb*cb, 0.0f));
        size_t base = OFF_T + ((size_t)(b*IMG + t))*16;
        wsf[base + d]     = ca + f*(cb - ca);
        wsf[base + 8 + d] = sa + f*(sb - sa);
    }
    __syncthreads();      /* all this block's global stores issued+drained */

    /* mesh handoff: publish 7 cells, consume 7 cells, reset own 7 */
    if (t == 0) {
        __threadfence();                          /* agent-scope release */
        #pragma unroll
        for (int cons = 0; cons < 8; ++cons)
            if (cons != d)
                __hip_atomic_store(&wsu[OFF_DONE + b*64 + d*8 + cons], MAGIC,
                                   __ATOMIC_RELAXED, __HIP_MEMORY_SCOPE_AGENT);
        for (int p = 0; p < 8; ++p) {
            if (p == d) continue;
            while (__hip_atomic_load(&wsu[OFF_DONE + b*64 + p*8 + d],
                                     __ATOMIC_RELAXED, __HIP_MEMORY_SCOPE_AGENT)
                   != MAGIC)
                __builtin_amdgcn_s_sleep(1);
        }
        __threadfence();                          /* agent-scope acquire */
        #pragma unroll
        for (int p = 0; p < 8; ++p)
            if (p != d)
                __hip_atomic_store(&wsu[OFF_DONE + b*64 + p*8 + d], 0u,
                                   __ATOMIC_RELAXED, __HIP_MEMORY_SCOPE_AGENT);
    }
    __syncthreads();

    /* resize rows [d*28, d*28+28): stage y-strip (28x16) to LDS, X from
       global table (L2-hot), arithmetic identical to R9's k_resize. */
    {
        const int R0 = d*28;
        const float* tb = wsf + OFF_T + (size_t)b*IMG*16;
        for (int e = t; e < 448; e += 1024) ylds[e] = tb[(size_t)R0*16 + e];
        __syncthreads();
        int tx = t & 255, ty = t >> 8;           /* 256 cols x 4 row-groups */
        bool active = (tx < IMG);
        int ox = min(tx, IMG - 1);
        const float4* xt = (const float4*)(tb + (size_t)ox*16);
        float4 cx0 = xt[0], cx1 = xt[1], sx0 = xt[2], sx1 = xt[3];
        const float4* av = (const float4*)(wsf + OFF_A + b*8);
        float4 a0 = av[0], a1 = av[1];
        float bias = 0.f;
        #pragma unroll
        for (int dd = 0; dd < 8; ++dd) bias += wsf[OFF_TERM + b*8 + dd];
        float mn = 1e30f, mx = -1e30f;
        #pragma unroll
        for (int rr = 0; rr < 7; ++rr) {
            int ry = ty*7 + rr;                  /* 0..27 within strip */
            const float* Y = ylds + ry*16;
            float acc;
            acc  = (a0.x*Y[0])*cx0.x - (a0.x*Y[ 8])*sx0.x;
            acc += (a0.y*Y[1])*cx0.y - (a0.y*Y[ 9])*sx0.y;
            acc += (a0.z*Y[2])*cx0.z - (a0.z*Y[10])*sx0.z;
            acc += (a0.w*Y[3])*cx0.w - (a0.w*Y[11])*sx0.w;
            acc += (a1.x*Y[4])*cx1.x - (a1.x*Y[12])*sx1.x;
            acc += (a1.y*Y[5])*cx1.y - (a1.y*Y[13])*sx1.y;
            acc += (a1.z*Y[6])*cx1.z - (a1.z*Y[14])*sx1.z;
            acc += (a1.w*Y[7])*cx1.w - (a1.w*Y[15])*sx1.w;
            float g = acc - bias;
            if (active) {
                int oy = R0 + ry;
                wsf[OFF_G + (size_t)b*PIX + (size_t)oy*IMG + ox] = g;
                mn = fminf(mn, g);
                mx = fmaxf(mx, g);
            }
        }
        block_minmax_share<1024>(mn, mx, red);
        if (t == 0) {
            wsf[OFF_GPMIN + bd] = red[0];
            wsf[OFF_GPMAX + bd] = red[1];
        }
    }
}

/* K2: reduce 128 g-partials (redundant per block), normalize, x3 write */
__global__ __launch_bounds__(256) void k_out(const float* __restrict__ wsf,
                                             float* __restrict__ out) {
    __shared__ float red[16];
    int t = threadIdx.x;
    float pmn = (t < 128) ? wsf[OFF_GPMIN + t] :  1e30f;
    float pmx = (t < 128) ? wsf[OFF_GPMAX + t] : -1e30f;
    block_minmax_share<256>(pmn, pmx, red);
    float gmin = red[0];
    float scale = 1.0f / ((red[1] - gmin) + 1e-6f);
    int idx = blockIdx.x*256 + t;                /* [0, 200704) float4 */
    float4 gv = ((const float4*)(wsf + OFF_G))[idx];
    float4 v;
    v.x = (gv.x - gmin)*scale;
    v.y = (gv.y - gmin)*scale;
    v.z = (gv.z - gmin)*scale;
    v.w = (gv.w - gmin)*scale;
    int b   = idx / (PIX/4);
    int rem = idx - b*(PIX/4);
    float4* ob = (float4*)(out + (size_t)b*3*PIX) + rem;
    ob[0]         = v;
    ob[PIX/4]     = v;
    ob[2*(PIX/4)] = v;
}

extern "C" void kernel_launch(void* const* d_in, const int* in_sizes, int n_in,
                              void* d_out, int out_size, void* d_ws, size_t ws_size,
                              hipStream_t stream) {
    const float* x = (const float*)d_in[0];
    float* out     = (float*)d_out;
    float* wsf     = (float*)d_ws;
    unsigned* wsu  = (unsigned*)d_ws;

    k_bd <<<NBD,            1024, 0, stream>>>(x, wsf, wsu);
    k_out<<<(B_*PIX/4)/256, 256,  0, stream>>>(wsf, out);
}